// Round 9
// baseline (115.598 us; speedup 1.0000x reference)
//
#include <hip/hip_runtime.h>

// UPCLoss, algebraically reduced (validated R7/R8, absmax 0.0):
//   N^2*loss = sum_i u_i*||x_i||^2 - 2 * sum_{c,k} W[c][k]*S[c][k]
//   [W;S] = [G2 | onehot]^T (32x512) . X (512x65536)  -> tall-skinny GEMM
//   u_i   = sum_c cnt[c]*G2[i][c] + H[label_i],  H[c] = sum_i G2[i][c]
// R8 was VALU-latency-bound (33 ops/elem). This version moves the 32
// per-element FMAs into 2 MFMAs per 32-row step: no LDS, no barriers,
// fragments loaded straight from global, validated layouts from R1-R6.

typedef float f32x4 __attribute__((ext_vector_type(4)));
typedef __bf16 bf16x8 __attribute__((ext_vector_type(8)));

constexpr int NROW = 512;
constexpr int KDIM = 65536;

__device__ __forceinline__ unsigned short bf16_bits(float v) {
    __bf16 h = (__bf16)v;
    unsigned short u;
    __builtin_memcpy(&u, &h, 2);
    return u;
}

// ---------- prep ----------
// Builds: g2a/g2s — MFMA A-fragment tables [16 steps][64 lanes][8] bf16
//   A[m=c][k] layout: lane l holds A[l&15][(l>>4)*8 + t], k = s*32 + klocal.
//   g2a[(s*64+l)*8+t] = G2[s*32+(l>>4)*8+t][l&15]; g2s likewise with onehot.
// utab[512] = u_i.
__global__ __launch_bounds__(512) void prep_kernel(const int* __restrict__ ranking,
                                                   const int* __restrict__ choice,
                                                   const int* __restrict__ ncp,
                                                   unsigned short* __restrict__ g2a,
                                                   unsigned short* __restrict__ g2s,
                                                   float* __restrict__ utab) {
    __shared__ float Hs[16];
    __shared__ int   cnt[16];
    int i = threadIdx.x;
    if (i < 16) { Hs[i] = 0.f; cnt[i] = 0; }
    __syncthreads();

    int rk[16];
#pragma unroll
    for (int q = 0; q < 16; ++q) rk[q] = ranking[i * 16 + q];
    int pos[16];
#pragma unroll
    for (int q = 0; q < 16; ++q) pos[rk[q]] = q;

    int   lbl = rk[0];
    float c   = (float)choice[i];
    float nc  = (float)(*ncp);
    atomicAdd(&cnt[lbl], 1);

    float grow[16];
#pragma unroll
    for (int q = 0; q < 16; ++q) {
        float r = (float)pos[q];
        float m = (r < c) ? (1.f - r / c) : (-(r - c + 1.f) / (nc - c));
        grow[q] = m * m;
        atomicAdd(&Hs[q], grow[q]);
    }

    // fragment writes: row i -> step s=i>>5, lane-group g=(i>>3)&3, t=i&7
    int s = i >> 5, g = (i >> 3) & 3, t = i & 7;
#pragma unroll
    for (int q = 0; q < 16; ++q) {
        int idx = (s * 64 + (g << 4) + q) * 8 + t;
        g2a[idx] = bf16_bits(grow[q]);
        g2s[idx] = bf16_bits(q == lbl ? 1.f : 0.f);
    }
    __syncthreads();

    float u = 0.f;
#pragma unroll
    for (int q = 0; q < 16; ++q) u += (float)cnt[q] * grow[q];
    u += Hs[lbl];
    utab[i] = u;
}

// ---------- main pass: 4096 waves, each owns 16 columns, K=512 ----------
__global__ __launch_bounds__(256, 4) void colpass(const float* __restrict__ X,
                                                  const unsigned short* __restrict__ g2a,
                                                  const unsigned short* __restrict__ g2s,
                                                  const float* __restrict__ utab,
                                                  float* __restrict__ acc) {
    int t    = threadIdx.x;
    int lane = t & 63;
    int wid  = blockIdx.x * 4 + (t >> 6);      // 0..4095
    int col  = wid * 16 + (lane & 15);
    int rg   = lane >> 4;                      // row-group 0..3
    const float* xp = X + (size_t)(rg * 8) * KDIM + col;

    f32x4 accw = {};
    f32x4 accs = {};
    float t1 = 0.f;

#pragma unroll 2
    for (int s = 0; s < 16; ++s) {
        // B-fragment: X[s*32 + rg*8 + tt][col], tt=0..7 (8 independent loads)
        float xv[8];
#pragma unroll
        for (int tt = 0; tt < 8; ++tt)
            xv[tt] = xp[(size_t)(s * 32 + tt) * KDIM];

        // A-fragments (coef tables, L2-resident) + u slice (L1-broadcast)
        bf16x8 aw = *reinterpret_cast<const bf16x8*>(g2a + (s * 64 + lane) * 8);
        bf16x8 as = *reinterpret_cast<const bf16x8*>(g2s + (s * 64 + lane) * 8);
        float4 u0 = *reinterpret_cast<const float4*>(utab + s * 32 + rg * 8);
        float4 u1 = *reinterpret_cast<const float4*>(utab + s * 32 + rg * 8 + 4);

        bf16x8 xb;
#pragma unroll
        for (int tt = 0; tt < 8; ++tt) xb[tt] = (__bf16)xv[tt];

        accw = __builtin_amdgcn_mfma_f32_16x16x32_bf16(aw, xb, accw, 0, 0, 0);
        accs = __builtin_amdgcn_mfma_f32_16x16x32_bf16(as, xb, accs, 0, 0, 0);

        t1 = fmaf(u0.x, xv[0] * xv[0], t1);
        t1 = fmaf(u0.y, xv[1] * xv[1], t1);
        t1 = fmaf(u0.z, xv[2] * xv[2], t1);
        t1 = fmaf(u0.w, xv[3] * xv[3], t1);
        t1 = fmaf(u1.x, xv[4] * xv[4], t1);
        t1 = fmaf(u1.y, xv[5] * xv[5], t1);
        t1 = fmaf(u1.z, xv[6] * xv[6], t1);
        t1 = fmaf(u1.w, xv[7] * xv[7], t1);
    }

    // lane holds W[c][j], S[c][j] for c=(lane>>4)*4+v, j=col. Every (c,j)
    // pair lives in exactly one lane of one wave -> global sum needs no
    // column-wise exchange: fold everything into one scalar.
    float cross = accw[0] * accs[0] + accw[1] * accs[1]
                + accw[2] * accs[2] + accw[3] * accs[3];
    float local = fmaf(-2.f, cross, t1);

#pragma unroll
    for (int off = 32; off > 0; off >>= 1) local += __shfl_down(local, off);
    if (lane == 0) atomicAdd(acc, local);
}

__global__ void finalize(const float* __restrict__ acc, float* __restrict__ out) {
    out[0] = acc[0] * (1.f / ((float)NROW * (float)NROW));
}

extern "C" void kernel_launch(void* const* d_in, const int* in_sizes, int n_in,
                              void* d_out, int out_size, void* d_ws, size_t ws_size,
                              hipStream_t stream) {
    const float* X       = (const float*)d_in[0];
    const int*   ranking = (const int*)d_in[1];
    const int*   choice  = (const int*)d_in[2];
    const int*   ncp     = (const int*)d_in[3];
    float*       ws      = (float*)d_ws;

    // ws: acc f32[4] | utab f32[512] | g2a u16[8192] | g2s u16[8192]
    float*          acc  = ws;
    float*          utab = ws + 4;
    unsigned short* g2a  = (unsigned short*)(ws + 4 + NROW);
    unsigned short* g2s  = g2a + 16 * 64 * 8;

    hipMemsetAsync(acc, 0, sizeof(float), stream);
    prep_kernel<<<dim3(1), dim3(512), 0, stream>>>(ranking, choice, ncp, g2a, g2s, utab);
    colpass<<<dim3(1024), dim3(256), 0, stream>>>(X, g2a, g2s, utab, acc);
    finalize<<<dim3(1), dim3(1), 0, stream>>>(acc, (float*)d_out);
}